// Round 3
// baseline (1913.393 us; speedup 1.0000x reference)
//
#include <hip/hip_runtime.h>

// B=64, S=512, I=256, O=256 fp32 LSTM.
// out = [h_seq (64*512*256)] [hT (64*256)] [cT (64*256)]
//
// Phase A: xg = x @ Wx^T + bx + bh  (fp32 LDS-tiled GEMM)
// Phase B: one block per batch, 256 threads (4 waves, 1 wave/SIMD, 512 VGPR
//   budget). Thread tid owns ALL FOUR gate rows at p=tid -> gate math and
//   c-update are thread-local (no io exchange). Wh fp16: k<224 in VGPRs
//   (4x112 half2 = 448 regs), k in [224,256) in LDS (64 KB). h in LDS fp16
//   (broadcast reads). LDS model: 48 ds_read_b128/thread/step x 4 waves
//   x 12 cyc = 2304 cyc/step.

#define SS 512
#define KR 224

typedef _Float16 h2 __attribute__((ext_vector_type(2)));

__device__ __forceinline__ h2 bch(unsigned u) { return __builtin_bit_cast(h2, u); }

#if __has_builtin(__builtin_amdgcn_fdot2)
__device__ __forceinline__ float dot2f(h2 a, h2 b, float c) {
  return __builtin_amdgcn_fdot2(a, b, c, false);
}
#else
__device__ __forceinline__ float dot2f(h2 a, h2 b, float c) {
  return c + (float)a[0] * (float)b[0] + (float)a[1] * (float)b[1];
}
#endif

__device__ __forceinline__ float sigm(float x) { return 1.f / (1.f + __expf(-x)); }
__device__ __forceinline__ float tanh_f(float x) {
  float e = __expf(-2.f * fabsf(x));
  float r = (1.f - e) / (1.f + e);
  return copysignf(r, x);
}

// ---------------------------------------------------------------- Phase A
__global__ __launch_bounds__(256) void xg_gemm(
    const float* __restrict__ X, const float* __restrict__ W,
    const float* __restrict__ bx, const float* __restrict__ bh,
    float* __restrict__ out)
{
  __shared__ float As[64][68];
  __shared__ float Bs[64][68];
  const int bm = blockIdx.x >> 4;
  const int bn = blockIdx.x & 15;
  const int tid = threadIdx.x;
  const int tn = tid & 15, tm = tid >> 4;
  const int row0 = bm * 64, col0 = bn * 64;
  float acc[4][4] = {};

  for (int k0 = 0; k0 < 256; k0 += 64) {
#pragma unroll
    for (int i = 0; i < 4; i++) {
      const int m = (tid >> 4) + i * 16;
      const int k = (tid & 15) * 4;
      float4 av = *(const float4*)&X[(size_t)(row0 + m) * 256 + k0 + k];
      *(float4*)&As[m][k] = av;
      float4 wv = *(const float4*)&W[(size_t)(col0 + m) * 256 + k0 + k];
      Bs[k + 0][m] = wv.x; Bs[k + 1][m] = wv.y;
      Bs[k + 2][m] = wv.z; Bs[k + 3][m] = wv.w;
    }
    __syncthreads();
#pragma unroll 8
    for (int kk = 0; kk < 64; kk++) {
      const float a0 = As[tm * 4 + 0][kk];
      const float a1 = As[tm * 4 + 1][kk];
      const float a2 = As[tm * 4 + 2][kk];
      const float a3 = As[tm * 4 + 3][kk];
      const float4 bv = *(const float4*)&Bs[kk][tn * 4];
      acc[0][0] = fmaf(a0, bv.x, acc[0][0]); acc[0][1] = fmaf(a0, bv.y, acc[0][1]);
      acc[0][2] = fmaf(a0, bv.z, acc[0][2]); acc[0][3] = fmaf(a0, bv.w, acc[0][3]);
      acc[1][0] = fmaf(a1, bv.x, acc[1][0]); acc[1][1] = fmaf(a1, bv.y, acc[1][1]);
      acc[1][2] = fmaf(a1, bv.z, acc[1][2]); acc[1][3] = fmaf(a1, bv.w, acc[1][3]);
      acc[2][0] = fmaf(a2, bv.x, acc[2][0]); acc[2][1] = fmaf(a2, bv.y, acc[2][1]);
      acc[2][2] = fmaf(a2, bv.z, acc[2][2]); acc[2][3] = fmaf(a2, bv.w, acc[2][3]);
      acc[3][0] = fmaf(a3, bv.x, acc[3][0]); acc[3][1] = fmaf(a3, bv.y, acc[3][1]);
      acc[3][2] = fmaf(a3, bv.z, acc[3][2]); acc[3][3] = fmaf(a3, bv.w, acc[3][3]);
    }
    __syncthreads();
  }

  float bias[4];
#pragma unroll
  for (int j = 0; j < 4; j++) {
    const int col = col0 + tn * 4 + j;
    bias[j] = bx[col] + bh[col];
  }
#pragma unroll
  for (int i = 0; i < 4; i++) {
    float4 o4;
    o4.x = acc[i][0] + bias[0]; o4.y = acc[i][1] + bias[1];
    o4.z = acc[i][2] + bias[2]; o4.w = acc[i][3] + bias[3];
    *(float4*)&out[(size_t)(row0 + tm * 4 + i) * 1024 + col0 + tn * 4] = o4;
  }
}

// ---------------------------------------------------------------- Phase B
__global__ __launch_bounds__(256, 1) void lstm_scan3(
    const float* __restrict__ xg,   // [64][512][1024]
    const float* __restrict__ Wh,   // [1024][256]
    const float* __restrict__ h0,   // [64][256]
    const float* __restrict__ c0,   // [64][256]
    float* __restrict__ out)
{
  // wl: [gate(4)][chunk(4)][tid(256)][8 halves] -> 16B contiguous per lane
  __shared__ __align__(16) _Float16 wl[4 * 4 * 256 * 8];   // 64 KB
  __shared__ __align__(16) _Float16 h_sh[256];

  const int tid = threadIdx.x;
  const int b = blockIdx.x;

  // ---- weights: thread owns rows {f,i,g,o} at p=tid
  h2 w[4][KR / 2];
#pragma unroll
  for (int g = 0; g < 4; ++g) {
    const float* r = Wh + ((size_t)(g * 256) + tid) * 256;
#pragma unroll
    for (int j = 0; j < KR / 2; ++j) {
      float2 a = *(const float2*)&r[2 * j];
      h2 v; v[0] = (_Float16)a.x; v[1] = (_Float16)a.y;
      w[g][j] = v;
    }
#pragma unroll
    for (int c = 0; c < 4; ++c)
#pragma unroll
      for (int e = 0; e < 8; ++e)
        wl[(((g * 4 + c) * 256) + tid) * 8 + e] = (_Float16)r[KR + c * 8 + e];
  }
  h_sh[tid] = (_Float16)h0[(size_t)b * 256 + tid];
  float cr = c0[(size_t)b * 256 + tid];
  __syncthreads();

  const float* xr = xg + (size_t)b * SS * 1024 + tid;
  float* hs = out + (size_t)b * SS * 256;

  float x0 = xr[0], x1 = xr[256], x2 = xr[512], x3 = xr[768];
  float hlast = 0.f;

  for (int t = 0; t < SS; ++t) {
    // prefetch next step's xg while we compute
    float nx0 = 0.f, nx1 = 0.f, nx2 = 0.f, nx3 = 0.f;
    if (t + 1 < SS) {
      const float* xn = xr + (size_t)(t + 1) * 1024;
      nx0 = xn[0]; nx1 = xn[256]; nx2 = xn[512]; nx3 = xn[768];
    }

    float a0 = x0, a1 = x1, a2 = x2, a3 = x3;   // xg already includes biases
    // k < KR: weights in VGPRs, h broadcast from LDS
#pragma unroll
    for (int c2 = 0; c2 < KR / 16; ++c2) {
      uint4 ha = *(const uint4*)&h_sh[c2 * 16];
      uint4 hb = *(const uint4*)&h_sh[c2 * 16 + 8];
      unsigned hv[8] = {ha.x, ha.y, ha.z, ha.w, hb.x, hb.y, hb.z, hb.w};
      const int j = c2 * 8;
#pragma unroll
      for (int u = 0; u < 8; ++u) {
        const h2 hh = bch(hv[u]);
        a0 = dot2f(w[0][j + u], hh, a0);
        a1 = dot2f(w[1][j + u], hh, a1);
        a2 = dot2f(w[2][j + u], hh, a2);
        a3 = dot2f(w[3][j + u], hh, a3);
      }
    }
    // k in [KR,256): weights in LDS
#pragma unroll
    for (int c = 0; c < 4; ++c) {
      uint4 hw = *(const uint4*)&h_sh[KR + c * 8];
      unsigned hv2[4] = {hw.x, hw.y, hw.z, hw.w};
      uint4 w0 = *(const uint4*)&wl[(((0 * 4 + c) * 256) + tid) * 8];
      uint4 w1 = *(const uint4*)&wl[(((1 * 4 + c) * 256) + tid) * 8];
      uint4 w2 = *(const uint4*)&wl[(((2 * 4 + c) * 256) + tid) * 8];
      uint4 w3 = *(const uint4*)&wl[(((3 * 4 + c) * 256) + tid) * 8];
      a0 = dot2f(bch(w0.x), bch(hv2[0]), a0); a0 = dot2f(bch(w0.y), bch(hv2[1]), a0);
      a0 = dot2f(bch(w0.z), bch(hv2[2]), a0); a0 = dot2f(bch(w0.w), bch(hv2[3]), a0);
      a1 = dot2f(bch(w1.x), bch(hv2[0]), a1); a1 = dot2f(bch(w1.y), bch(hv2[1]), a1);
      a1 = dot2f(bch(w1.z), bch(hv2[2]), a1); a1 = dot2f(bch(w1.w), bch(hv2[3]), a1);
      a2 = dot2f(bch(w2.x), bch(hv2[0]), a2); a2 = dot2f(bch(w2.y), bch(hv2[1]), a2);
      a2 = dot2f(bch(w2.z), bch(hv2[2]), a2); a2 = dot2f(bch(w2.w), bch(hv2[3]), a2);
      a3 = dot2f(bch(w3.x), bch(hv2[0]), a3); a3 = dot2f(bch(w3.y), bch(hv2[1]), a3);
      a3 = dot2f(bch(w3.z), bch(hv2[2]), a3); a3 = dot2f(bch(w3.w), bch(hv2[3]), a3);
    }

    // thread-local gates + state update  (gate order f,i,g,o)
    const float fg = sigm(a0);
    const float ig = sigm(a1);
    const float gt = tanh_f(a2);
    const float og = sigm(a3);
    cr = cr * fg + ig * gt;
    const float h = og * tanh_f(cr);
    hlast = h;

    __syncthreads();                     // all waves done reading h_sh
    h_sh[tid] = (_Float16)h;
    hs[(size_t)t * 256 + tid] = h;
    x0 = nx0; x1 = nx1; x2 = nx2; x3 = nx3;
    __syncthreads();                     // h_sh(t) visible to all
  }

  out[8388608 + (size_t)b * 256 + tid] = hlast;   // hT
  out[8404992 + (size_t)b * 256 + tid] = cr;      // cT
}

// ---------------------------------------------------------------- launch
extern "C" void kernel_launch(void* const* d_in, const int* in_sizes, int n_in,
                              void* d_out, int out_size, void* d_ws, size_t ws_size,
                              hipStream_t stream) {
  const float* x  = (const float*)d_in[0];
  const float* h0 = (const float*)d_in[1];
  const float* c0 = (const float*)d_in[2];
  const float* Wh = (const float*)d_in[3];
  const float* bh = (const float*)d_in[4];
  const float* Wx = (const float*)d_in[5];
  const float* bx = (const float*)d_in[6];
  float* out = (float*)d_out;

  float* xg = (float*)d_ws;   // 32768*1024 floats = 128 MB

  xg_gemm<<<dim3(8192), dim3(256), 0, stream>>>(x, Wx, bx, bh, xg);
  lstm_scan3<<<dim3(64), dim3(256), 0, stream>>>(xg, Wh, h0, c0, out);
}